// Round 12
// baseline (218.217 us; speedup 1.0000x reference)
//
#include <hip/hip_runtime.h>
#include <hip/hip_cooperative_groups.h>

namespace cg = cooperative_groups;

#define T      64
#define S      32
#define NGRAPH 64
#define NSPLIT 16     // slices per graph -> 1024 blocks of 256 (4 blocks/CU)
#define NW     4
#define XCAP   128    // staged-node capacity (x4: 128 nodes * 16B = 2 KB)

// R18: single cooperative dispatch. R17 was neutral vs R15 because it kept
// the same dispatch count (memset replaced reduce); the residual ~15us is
// dispatch boundaries (~4-6us each), not inner-loop work. Fuse: phase A =
// R17 body -> prefixed slice partials to ws (plain stores, no atomics, no
// memset), threadfence + grid.sync(), phase B = float2 reduce ws -> out.
// Cooperative co-residency: 1024 blocks @ launch_bounds(256,4) = 4/CU x
// 256 CU exactly; LDS 34816B x 4 = 136KB <= 160KB; VGPR<=128 (measured 52).
// Fallback (coop launch rejected): same phase A as a plain kernel + the
// R15 float2 reduce -> identical numerics, R15 timing.
//
// Body (R17, validated absmax 4.0): x staged to LDS padded [n][4] -> one
// uniform ds_read_b128/node; bins = 2 half-arrays [32][128], wave pair ->
// own half, col=(w&1)*64+t: bank = col mod 32 (conflict-free, slot-
// independent), slot rows 128 dwords apart (ds_read2/write2 mergeable).
// Slot triple rebased to contiguous rows pb,pb+1,pb+2 (pb=med3(ss-1,0,29))
// with per-row amount select -- case-verified identical to the R9/R10
// delta encoding (row 0 = trash, overwritten by v0acc; clamped rows +0.0).
__device__ __forceinline__ void ect_phaseA(
    const float* __restrict__ x, const float* __restrict__ v,
    const float* __restrict__ lin, const int* __restrict__ batch,
    float* __restrict__ ws, int n_points,
    float (*bins)[32][128], float* x4)
{
    const int tid  = threadIdx.x;
    const int t    = tid & 63;       // lane == theta
    const int w    = __builtin_amdgcn_readfirstlane(tid >> 6); // wave id, SGPR
    const int half = w >> 1;
    const int col  = ((w & 1) << 6) + t;
    float* bw = &bins[half][0][0];   // this wave's half-array
    const int b    = blockIdx.x;
    const int g    = b >> 4;         // graph
    const int c    = b & (NSPLIT - 1);

    {   // vectorized zero-init: 8192 dwords = 2048 float4, 8 per thread
        const float4 z4 = {0.0f, 0.0f, 0.0f, 0.0f};
        float4* b4 = (float4*)&bins[0][0][0];
#pragma unroll
        for (int i = 0; i < 8; i++) b4[tid + i * 256] = z4;
    }

    // 32-ary ballot search (lanes<32: lower_bound(g), >=32: lower_bound(g+1))
    const int target = (t < 32) ? g : (g + 1);
    const int i32    = t & 31;
    int lo = 0;
    const int strides[3] = {2048, 64, 2};
#pragma unroll
    for (int rnd = 0; rnd < 3; rnd++) {
        const int stride = strides[rnd];
        const int idx  = lo + i32 * stride;
        const int pv   = batch[min(idx, n_points - 1)];
        const bool prd = (idx < n_points) && (pv < target);
        const unsigned long long bal = __ballot(prd);
        const int cnt = __popc((unsigned)(bal >> (t & 32)));
        lo += max(cnt - 1, 0) * stride;
    }
    if ((lo < n_points) && (batch[min(lo, n_points - 1)] < target)) lo++;
    const int gstart = __builtin_amdgcn_readfirstlane(lo);
    const int gend   = __builtin_amdgcn_readlane(lo, 32);
    const int len    = gend - gstart;
    const int n0     = gstart + (len * c) / NSPLIT;
    const int n1     = gstart + (len * (c + 1)) / NSPLIT;
    const int sliceLen = n1 - n0;

    {   // coalesced staging into padded [n][4] layout (<=2 dwords/thread)
        const int limit = 3 * min(sliceLen, XCAP);
        const int base3 = 3 * n0;
        for (int p = tid; p < limit; p += 256) {
            const int n = p / 3;              // magic-mul, compiler
            const int d = p - 3 * n;
            x4[n * 4 + d] = x[base3 + p];     // base3+p < 3*n1 <= 3*n_points
        }
    }

    const float lin0     = lin[0];
    const float step     = lin[1] - lin0;
    const float inv_step = 1.0f / step;
    const float nl0i     = -lin0 * inv_step;
    const float K2 = (100.0f * step) * 1.4426950408889634f;   // ~10.24
    const float r  = __builtin_amdgcn_exp2f(-K2);

    const float v0 = v[0 * T + t];
    const float v1 = v[1 * T + t];
    const float v2 = v[2 * T + t];

    float v0acc = 0.0f;                 // profile value at s=0
    __syncthreads();                    // init + staging complete

#define ECT_BODY(X0, X1, X2)                                                  \
    {                                                                         \
        const float nh = fmaf((X0), v0, fmaf((X1), v1, (X2) * v2));           \
        const float f  = fmaf(nh, inv_step, nl0i);                            \
        const float fs = ceilf(f);                                            \
        const int   ss = (int)fs;                                             \
        const float e0 = __builtin_amdgcn_exp2f(fmaf(K2, f - fs, K2));        \
        const float e1 = e0 * r;                                              \
        const float sm  = __builtin_amdgcn_rcpf(1.0f + e0);                   \
        const float s0v = __builtin_amdgcn_rcpf(1.0f + e1);                   \
        v0acc += (ss <= -1) ? 1.0f : (ss == 0 ? s0v : (ss == 1 ? sm : 0.0f)); \
        const float d1 = s0v - sm, d2 = 1.0f - s0v;                           \
        const int pb = min(max(ss - 1, 0), 29);        /* v_med3_i32 */       \
        const float amt0 = (pb     == ss - 1) ? sm : 0.0f;                    \
        const float amt1 = (pb + 1 == ss    ) ? d1                            \
                         : (pb + 1 == ss + 1) ? d2                            \
                         : (pb + 1 == ss - 1) ? sm : 0.0f;                    \
        const float amt2 = (pb + 2 == ss + 1) ? d2                            \
                         : (pb + 2 == ss    ) ? d1                            \
                         : (pb + 2 == ss - 1) ? sm : 0.0f;                    \
        const int a = pb * 128 + col;                                         \
        const float r0 = bw[a], r1 = bw[a + 128], r2 = bw[a + 256];           \
        bw[a]       = r0 + amt0;                                              \
        bw[a + 128] = r1 + amt1;                                              \
        bw[a + 256] = r2 + amt2;                                              \
    }

    if (sliceLen <= XCAP) {             // staged path (always, in practice)
#pragma unroll 4
        for (int n = w; n < sliceLen; n += NW) {
            const float4 xv = *(const float4*)&x4[n * 4]; // uniform b128
            ECT_BODY(xv.x, xv.y, xv.z)
        }
    } else {                            // safety fallback: direct global
#pragma unroll 2
        for (int n = n0 + w; n < n1; n += NW) {
            const float x0 = x[3 * n + 0];
            const float x1 = x[3 * n + 1];
            const float x2 = x[3 * n + 2];
            ECT_BODY(x0, x1, x2)
        }
    }
#undef ECT_BODY

    bw[col] = v0acc;                    // row 0 of own half: base value
    __syncthreads();

    // merge 4 columns (2 per half) into bins[0][cc][tt]
    for (int cell = tid; cell < 32 * 64; cell += 256) {
        const int cc = cell >> 6;               // 0..31
        const int tt = cell & 63;
        const float sum = bins[0][cc][tt] + bins[0][cc][64 + tt]
                        + bins[1][cc][tt] + bins[1][cc][64 + tt];
        bins[0][cc][tt] = sum;          // read/write same cell same thread
    }
    __syncthreads();

    // prefix over rows, coalesced store of this slice's partial to ws
    float run = bins[0][0][t];                  // base = value at s=0
    const int sbase = 8 * w;
    for (int cc = 1; cc < sbase; cc++) run += bins[0][cc][t];
    float* wsb = ws + (size_t)b * (S * T);
#pragma unroll
    for (int j = 0; j < 8; j++) {
        const int s = sbase + j;
        if (s >= 1) run += bins[0][s][t];
        wsb[s * T + t] = run;
    }
}

__device__ __forceinline__ void ect_phaseB_elem(
    const float2* __restrict__ ws2, float2* __restrict__ out2, int idx)
{
    const int g = idx >> 10;                    // 1024 float2 per graph
    const int i = idx & 1023;
    float2 sum = {0.0f, 0.0f};
#pragma unroll
    for (int c = 0; c < NSPLIT; c++) {
        const float2 a = ws2[(size_t)(g * NSPLIT + c) * 1024 + i];
        sum.x += a.x; sum.y += a.y;
    }
    out2[idx] = sum;
}

// single cooperative dispatch: phase A -> grid sync -> phase B
__global__ __launch_bounds__(256, 4) void ect_fused(
    const float* __restrict__ x, const float* __restrict__ v,
    const float* __restrict__ lin, const int* __restrict__ batch,
    float* __restrict__ ws, float* __restrict__ out, int n_points)
{
    __shared__ float bins[2][32][128];
    __shared__ float x4[XCAP * 4];
    ect_phaseA(x, v, lin, batch, ws, n_points, bins, x4);

    __threadfence();                    // ws visible device-wide
    cg::this_grid().sync();

    const int idx = blockIdx.x * 256 + threadIdx.x;
    if (idx < NGRAPH * S * T / 2)       // blocks 0..255 active
        ect_phaseB_elem((const float2*)ws, (float2*)out, idx);
}

// fallback pair (coop launch rejected): identical numerics, 2 dispatches
__global__ __launch_bounds__(256, 4) void ect_partial_ws(
    const float* __restrict__ x, const float* __restrict__ v,
    const float* __restrict__ lin, const int* __restrict__ batch,
    float* __restrict__ ws, int n_points)
{
    __shared__ float bins[2][32][128];
    __shared__ float x4[XCAP * 4];
    ect_phaseA(x, v, lin, batch, ws, n_points, bins, x4);
}

__global__ __launch_bounds__(256) void ect_reduce(
    const float2* __restrict__ ws2, float2* __restrict__ out2)
{
    const int idx = blockIdx.x * 256 + threadIdx.x;  // [0, 65536)
    ect_phaseB_elem(ws2, out2, idx);
}

extern "C" void kernel_launch(void* const* d_in, const int* in_sizes, int n_in,
                              void* d_out, int out_size, void* d_ws, size_t ws_size,
                              hipStream_t stream) {
    const float* x     = (const float*)d_in[0];
    const float* v     = (const float*)d_in[1];
    const float* lin   = (const float*)d_in[2];
    const int*   batch = (const int*)d_in[3];
    float* out = (float*)d_out;
    float* ws  = (float*)d_ws;                   // 1024 * 2048 floats = 8.4 MB

    const int n_points = in_sizes[0] / 3;

    void* kargs[] = {(void*)&x, (void*)&v, (void*)&lin, (void*)&batch,
                     (void*)&ws, (void*)&out, (void*)&n_points};
    const hipError_t e = hipLaunchCooperativeKernel(
        (const void*)ect_fused, dim3(NGRAPH * NSPLIT), dim3(256),
        kargs, 0, stream);
    if (e != hipSuccess) {              // fallback: classic two-dispatch
        ect_partial_ws<<<NGRAPH * NSPLIT, 256, 0, stream>>>(
            x, v, lin, batch, ws, n_points);
        ect_reduce<<<NGRAPH * S * T / 2 / 256, 256, 0, stream>>>(
            (const float2*)ws, (float2*)out);
    }
}

// Round 18
// 77.730 us; speedup vs baseline: 2.8074x; 2.8074x over previous
//
#include <hip/hip_runtime.h>

#define T      64
#define S      32
#define NGRAPH 64
#define NSPLIT 32     // slices per graph -> 2048 blocks of 128 (9 blocks/CU)
#define NW     2      // waves per block
#define XCAP   64     // staged-node capacity (x4: 64 nodes * 16B = 1 KB)

// R19: occupancy via smaller blocks. R18 post-mortem: grid.sync() costs
// ~130us on 8 non-coherent XCDs (spin via HBM/L3) -- cooperative fusion
// dead; R17 (atomic-fused reduce) was neutral -> dispatch structure is not
// the residual; the lever is partial's duration. At 256-thr blocks LDS
// (34.8KB) caps 4 blocks/CU = 16 waves/CU. 128-thr blocks: bins [32][128]
// = 16KB + 1KB x4 -> 9 blocks/CU = 18 waves/CU, finer ramp/tail (2048
// blocks), 2-column merge epilogue (was 4).
//
// Body = R17 (validated absmax 4.0): x staged padded [n][4] -> one uniform
// ds_read_b128/node; bins col = w*64+t (bank = col mod 32, slot-
// independent, conflict-free); slot triple rebased to contiguous rows
// pb,pb+1,pb+2 (pb=med3(ss-1,0,29)), rows 128 dwords apart
// (ds_read2/write2 mergeable); per-row amount select case-verified
// identical to the R9/R10 delta encoding (row 0 = trash, overwritten by
// v0acc; clamped rows +0.0).
__global__ __launch_bounds__(128, 4) void ect_partial(
    const float* __restrict__ x, const float* __restrict__ v,
    const float* __restrict__ lin, const int* __restrict__ batch,
    float* __restrict__ ws, int n_points)
{
    __shared__ float bins[32][128]; // [row][col]; row 0 base+trash
    __shared__ float x4[XCAP * 4];  // staged x, padded to 16B/node

    const int tid  = threadIdx.x;
    const int t    = tid & 63;       // lane == theta
    const int w    = __builtin_amdgcn_readfirstlane(tid >> 6); // 0..1
    const int col  = (w << 6) + t;
    float* bw = &bins[0][0];
    const int b    = blockIdx.x;
    const int g    = b >> 5;         // graph
    const int c    = b & (NSPLIT - 1);

    {   // vectorized zero-init: 4096 dwords = 1024 float4, 8 per thread
        const float4 z4 = {0.0f, 0.0f, 0.0f, 0.0f};
        float4* b4 = (float4*)&bins[0][0];
#pragma unroll
        for (int i = 0; i < 8; i++) b4[tid + i * 128] = z4;
    }

    // 32-ary ballot search (lanes<32: lower_bound(g), >=32: lower_bound(g+1))
    const int target = (t < 32) ? g : (g + 1);
    const int i32    = t & 31;
    int lo = 0;
    const int strides[3] = {2048, 64, 2};
#pragma unroll
    for (int rnd = 0; rnd < 3; rnd++) {
        const int stride = strides[rnd];
        const int idx  = lo + i32 * stride;
        const int pv   = batch[min(idx, n_points - 1)];
        const bool prd = (idx < n_points) && (pv < target);
        const unsigned long long bal = __ballot(prd);
        const int cnt = __popc((unsigned)(bal >> (t & 32)));
        lo += max(cnt - 1, 0) * stride;
    }
    if ((lo < n_points) && (batch[min(lo, n_points - 1)] < target)) lo++;
    const int gstart = __builtin_amdgcn_readfirstlane(lo);
    const int gend   = __builtin_amdgcn_readlane(lo, 32);
    const int len    = gend - gstart;
    const int n0     = gstart + (len * c) / NSPLIT;
    const int n1     = gstart + (len * (c + 1)) / NSPLIT;
    const int sliceLen = n1 - n0;

    {   // coalesced staging into padded [n][4] layout (<=2 dwords/thread)
        const int limit = 3 * min(sliceLen, XCAP);
        const int base3 = 3 * n0;
        for (int p = tid; p < limit; p += 128) {
            const int n = p / 3;              // magic-mul, compiler
            const int d = p - 3 * n;
            x4[n * 4 + d] = x[base3 + p];     // base3+p < 3*n1 <= 3*n_points
        }
    }

    const float lin0     = lin[0];
    const float step     = lin[1] - lin0;
    const float inv_step = 1.0f / step;
    const float nl0i     = -lin0 * inv_step;
    const float K2 = (100.0f * step) * 1.4426950408889634f;   // ~10.24
    const float r  = __builtin_amdgcn_exp2f(-K2);

    const float v0 = v[0 * T + t];
    const float v1 = v[1 * T + t];
    const float v2 = v[2 * T + t];

    float v0acc = 0.0f;                 // profile value at s=0
    __syncthreads();                    // init + staging complete

#define ECT_BODY(X0, X1, X2)                                                  \
    {                                                                         \
        const float nh = fmaf((X0), v0, fmaf((X1), v1, (X2) * v2));           \
        const float f  = fmaf(nh, inv_step, nl0i);                            \
        const float fs = ceilf(f);                                            \
        const int   ss = (int)fs;                                             \
        const float e0 = __builtin_amdgcn_exp2f(fmaf(K2, f - fs, K2));        \
        const float e1 = e0 * r;                                              \
        const float sm  = __builtin_amdgcn_rcpf(1.0f + e0);                   \
        const float s0v = __builtin_amdgcn_rcpf(1.0f + e1);                   \
        v0acc += (ss <= -1) ? 1.0f : (ss == 0 ? s0v : (ss == 1 ? sm : 0.0f)); \
        const float d1 = s0v - sm, d2 = 1.0f - s0v;                           \
        const int pb = min(max(ss - 1, 0), 29);        /* v_med3_i32 */       \
        const float amt0 = (pb     == ss - 1) ? sm : 0.0f;                    \
        const float amt1 = (pb + 1 == ss    ) ? d1                            \
                         : (pb + 1 == ss + 1) ? d2                            \
                         : (pb + 1 == ss - 1) ? sm : 0.0f;                    \
        const float amt2 = (pb + 2 == ss + 1) ? d2                            \
                         : (pb + 2 == ss    ) ? d1                            \
                         : (pb + 2 == ss - 1) ? sm : 0.0f;                    \
        const int a = pb * 128 + col;                                         \
        const float r0 = bw[a], r1 = bw[a + 128], r2 = bw[a + 256];           \
        bw[a]       = r0 + amt0;                                              \
        bw[a + 128] = r1 + amt1;                                              \
        bw[a + 256] = r2 + amt2;                                              \
    }

    if (sliceLen <= XCAP) {             // staged path (always, in practice)
#pragma unroll 4
        for (int n = w; n < sliceLen; n += NW) {
            const float4 xv = *(const float4*)&x4[n * 4]; // uniform b128
            ECT_BODY(xv.x, xv.y, xv.z)
        }
    } else {                            // safety fallback: direct global
#pragma unroll 2
        for (int n = n0 + w; n < n1; n += NW) {
            const float x0 = x[3 * n + 0];
            const float x1 = x[3 * n + 1];
            const float x2 = x[3 * n + 2];
            ECT_BODY(x0, x1, x2)
        }
    }
#undef ECT_BODY

    bins[0][col] = v0acc;               // row 0: overwrites in-loop trash
    __syncthreads();

    // merge 2 wave-columns into bins[cc][tt] (cc = 0..31)
    for (int cell = tid; cell < 32 * 64; cell += 128) {
        const int cc = cell >> 6;
        const int tt = cell & 63;
        bins[cc][tt] = bins[cc][tt] + bins[cc][64 + tt]; // same-thread RMW
    }
    __syncthreads();

    // prefix over rows, coalesced store: wave w covers s in [16w, 16w+16)
    float run = bins[0][t];                     // base = value at s=0
    const int sbase = 16 * w;
    for (int cc = 1; cc < sbase; cc++) run += bins[cc][t];
    float* wsb = ws + (size_t)b * (S * T);
#pragma unroll
    for (int j = 0; j < 16; j++) {
        const int s = sbase + j;
        if (s >= 1) run += bins[s][t];
        wsb[s * T + t] = run;
    }
}

// Phase 2: out[g][i] = sum of 32 slice partials, float2-wide.
// 256 blocks cover all 256 CUs; ws (16.8 MB) is L2/L3-resident.
__global__ __launch_bounds__(256) void ect_reduce(
    const float2* __restrict__ ws2, float2* __restrict__ out2)
{
    const int idx = blockIdx.x * 256 + threadIdx.x;  // [0, 65536)
    const int g   = idx >> 10;                       // 1024 float2 per graph
    const int i   = idx & 1023;
    float2 sum = {0.0f, 0.0f};
#pragma unroll
    for (int c = 0; c < NSPLIT; c++) {
        const float2 a = ws2[(size_t)(g * NSPLIT + c) * 1024 + i];
        sum.x += a.x; sum.y += a.y;
    }
    out2[idx] = sum;
}

extern "C" void kernel_launch(void* const* d_in, const int* in_sizes, int n_in,
                              void* d_out, int out_size, void* d_ws, size_t ws_size,
                              hipStream_t stream) {
    const float* x     = (const float*)d_in[0];
    const float* v     = (const float*)d_in[1];
    const float* lin   = (const float*)d_in[2];
    const int*   batch = (const int*)d_in[3];
    float* out = (float*)d_out;
    float* ws  = (float*)d_ws;                   // 2048 * 2048 floats = 16.8 MB

    const int n_points = in_sizes[0] / 3;

    ect_partial<<<NGRAPH * NSPLIT, 128, 0, stream>>>(x, v, lin, batch, ws, n_points);
    ect_reduce<<<NGRAPH * S * T / 2 / 256, 256, 0, stream>>>(
        (const float2*)ws, (float2*)out);
}

// Round 19
// 72.567 us; speedup vs baseline: 3.0071x; 1.0711x over previous
//
#include <hip/hip_runtime.h>

#define T      64
#define S      32
#define NGRAPH 64
#define NSPLIT 16     // slices per graph -> 1024 blocks of 256 (4 blocks/CU)
#define NW     4
#define TRASH  32     // row 32 is never read (valid delta rows are 1..31)
#define XCAP   170    // staged-node capacity (512 dwords of x_lds)

// R21 = R15 verbatim (best harness-verified: 71.68 us). Nine measured
// variants later (SGPR staging R16 ~+2us, wide-DS+atomic-fuse R17 neutral,
// cooperative fusion R18 +76us, 128-thr occupancy R19 neutral-on-slow-run),
// R15 remains the minimum. Partial duration is ~14us across all inner-loop
// structures -> block-level fixed costs dominate, and the timed region is
// harness-floor-dominated: 256MB poison fill ~41us (at ITS HBM roofline)
// + ~15us dispatch boundaries + partial ~14 + reduce ~1.5.
//
// Structure: cooperative coalesced staging of the slice's x into LDS (one
// overlapped HBM round trip, then uniform-addr broadcast ds_reads), 4
// blocks/CU; bins TRANSPOSED bins[c*256+tid] -> bank = tid mod 32,
// independent of data-dependent slot c (conflict-free by construction).
// Numerics (R9/R10-validated, absmax 4.0): per (node,theta) profile is
// 0..0, sm, s0, ~1..1; 3 deltas at slots ss-1, ss, ss+1 (third ~ 1-s0v,
// err <= 8.2e-4); slots <= 0 fold into base register; slots >= 32 -> trash.
__global__ __launch_bounds__(256, 4) void ect_partial(
    const float* __restrict__ x, const float* __restrict__ v,
    const float* __restrict__ lin, const int* __restrict__ batch,
    float* __restrict__ ws, int n_points)
{
    __shared__ float bins[33 * 256]; // [c][tid]: c=0 base, 1..31 deltas, 32 trash
    __shared__ float x_lds[512];     // staged x for this slice (<=170 nodes)

    const int tid  = threadIdx.x;
    const int t    = tid & 63;       // lane == theta
    const int w    = __builtin_amdgcn_readfirstlane(tid >> 6); // wave id, SGPR
    const int b    = blockIdx.x;
    const int g    = b >> 4;         // graph
    const int c    = b & (NSPLIT - 1);

    {   // vectorized zero-init of rows 0..32: 2112 float4
        const float4 z4 = {0.0f, 0.0f, 0.0f, 0.0f};
        float4* b4 = (float4*)bins;
        for (int i = tid; i < 33 * 256 / 4; i += 256) b4[i] = z4;
    }

    // 32-ary ballot search (lanes<32: lower_bound(g), >=32: lower_bound(g+1))
    const int target = (t < 32) ? g : (g + 1);
    const int i32    = t & 31;
    int lo = 0;
    const int strides[3] = {2048, 64, 2};
#pragma unroll
    for (int rnd = 0; rnd < 3; rnd++) {
        const int stride = strides[rnd];
        const int idx  = lo + i32 * stride;
        const int pv   = batch[min(idx, n_points - 1)];
        const bool prd = (idx < n_points) && (pv < target);
        const unsigned long long bal = __ballot(prd);
        const int cnt = __popc((unsigned)(bal >> (t & 32)));
        lo += max(cnt - 1, 0) * stride;
    }
    if ((lo < n_points) && (batch[min(lo, n_points - 1)] < target)) lo++;
    const int gstart = __builtin_amdgcn_readfirstlane(lo);
    const int gend   = __builtin_amdgcn_readlane(lo, 32);
    const int len    = gend - gstart;
    const int n0     = gstart + (len * c) / NSPLIT;
    const int n1     = gstart + (len * (c + 1)) / NSPLIT;
    const int sliceLen = n1 - n0;

    {   // coalesced staging: x[3*n0 .. 3*n1) -> x_lds (<=2 dwords/thread)
        const int base3 = 3 * n0;
        const int limit = 3 * min(sliceLen, XCAP);
        for (int p = tid; p < limit; p += 256)
            x_lds[p] = x[base3 + p];     // base3+p < 3*n1 <= 3*n_points
    }

    const float lin0     = lin[0];
    const float step     = lin[1] - lin0;
    const float inv_step = 1.0f / step;
    const float nl0i     = -lin0 * inv_step;
    const float K2 = (100.0f * step) * 1.4426950408889634f;   // ~10.24
    const float r  = __builtin_amdgcn_exp2f(-K2);

    const float v0 = v[0 * T + t];
    const float v1 = v[1 * T + t];
    const float v2 = v[2 * T + t];

    float v0acc = 0.0f;                 // profile value at s=0
    __syncthreads();                    // init + staging complete

#define ECT_BODY(X0, X1, X2)                                                  \
    {                                                                         \
        const float nh = fmaf((X0), v0, fmaf((X1), v1, (X2) * v2));           \
        const float f  = fmaf(nh, inv_step, nl0i);                            \
        const float fs = ceilf(f);                                            \
        const int   ss = (int)fs;                                             \
        const float e0 = __builtin_amdgcn_exp2f(fmaf(K2, f - fs, K2));        \
        const float e1 = e0 * r;                                              \
        const float sm  = __builtin_amdgcn_rcpf(1.0f + e0);                   \
        const float s0v = __builtin_amdgcn_rcpf(1.0f + e1);                   \
        v0acc += (ss <= -1) ? 1.0f : (ss == 0 ? s0v : (ss == 1 ? sm : 0.0f)); \
        const int p0 = ss - 1, p1 = ss, p2 = ss + 1;                          \
        const int a0 = (((unsigned)(p0 - 1) < 31u) ? p0 : TRASH) * 256 + tid; \
        const int a1 = (((unsigned)(p1 - 1) < 31u) ? p1 : TRASH) * 256 + tid; \
        const int a2 = (((unsigned)(p2 - 1) < 31u) ? p2 : TRASH) * 256 + tid; \
        const float r0 = bins[a0], r1 = bins[a1], r2 = bins[a2];              \
        bins[a0] = r0 + sm;                                                   \
        bins[a1] = r1 + (s0v - sm);                                           \
        bins[a2] = r2 + (1.0f - s0v);                                         \
    }

    if (sliceLen <= XCAP) {             // staged path (always, in practice)
#pragma unroll 4
        for (int n = n0 + w; n < n1; n += NW) {
            const int li3 = 3 * (n - n0);
            const float x0 = x_lds[li3 + 0];   // uniform addr -> broadcast
            const float x1 = x_lds[li3 + 1];
            const float x2 = x_lds[li3 + 2];
            ECT_BODY(x0, x1, x2)
        }
    } else {                            // safety fallback: direct global
#pragma unroll 2
        for (int n = n0 + w; n < n1; n += NW) {
            const float x0 = x[3 * n + 0];
            const float x1 = x[3 * n + 1];
            const float x2 = x[3 * n + 2];
            ECT_BODY(x0, x1, x2)
        }
    }
#undef ECT_BODY

    bins[0 * 256 + tid] = v0acc;
    __syncthreads();

    // merge 4 wave-lanes into tid = t (c = 0..31; trash skipped)
    for (int cell = tid; cell < 32 * 64; cell += 256) {
        const int cc = cell >> 6;               // 0..31
        const int tt = cell & 63;
        const float sum = bins[cc * 256 +   0 + tt] + bins[cc * 256 +  64 + tt]
                        + bins[cc * 256 + 128 + tt] + bins[cc * 256 + 192 + tt];
        bins[cc * 256 + tt] = sum;              // same-thread RMW, safe
    }
    __syncthreads();

    // prefix over c and coalesced store: wave w covers s in [8w, 8w+8)
    float run = bins[0 * 256 + t];              // base = value at s=0
    const int sbase = 8 * w;
    for (int cc = 1; cc < sbase; cc++) run += bins[cc * 256 + t];
    float* wsb = ws + (size_t)b * (S * T);
#pragma unroll
    for (int j = 0; j < 8; j++) {
        const int s = sbase + j;
        if (s >= 1) run += bins[s * 256 + t];
        wsb[s * T + t] = run;
    }
}

// Phase 2: out[g][i] = sum of 16 prefixed slice partials, float2-wide.
// 256 blocks cover all 256 CUs.
__global__ __launch_bounds__(256) void ect_reduce(
    const float2* __restrict__ ws2, float2* __restrict__ out2)
{
    const int idx = blockIdx.x * 256 + threadIdx.x;  // [0, 64*1024)
    const int g   = idx >> 10;                       // 1024 float2 per graph
    const int i   = idx & 1023;
    float2 sum = {0.0f, 0.0f};
#pragma unroll
    for (int c = 0; c < NSPLIT; c++) {
        const float2 a = ws2[(size_t)(g * NSPLIT + c) * 1024 + i];
        sum.x += a.x; sum.y += a.y;
    }
    out2[idx] = sum;
}

extern "C" void kernel_launch(void* const* d_in, const int* in_sizes, int n_in,
                              void* d_out, int out_size, void* d_ws, size_t ws_size,
                              hipStream_t stream) {
    const float* x     = (const float*)d_in[0];
    const float* v     = (const float*)d_in[1];
    const float* lin   = (const float*)d_in[2];
    const int*   batch = (const int*)d_in[3];
    float* out = (float*)d_out;
    float* ws  = (float*)d_ws;                   // 1024 * 2048 floats = 8.4 MB

    const int n_points = in_sizes[0] / 3;

    ect_partial<<<NGRAPH * NSPLIT, 256, 0, stream>>>(x, v, lin, batch, ws, n_points);
    ect_reduce<<<NGRAPH * S * T / 2 / 256, 256, 0, stream>>>(
        (const float2*)ws, (float2*)out);
}